// Round 15
// baseline (842.609 us; speedup 1.0000x reference)
//
#include <hip/hip_runtime.h>

#define NODE_DIM 256
#define HIDDEN 64
#define NUM_REL 10

#define FMA4(A, S, W) do { \
    (A).x = fmaf((S), (W).x, (A).x); \
    (A).y = fmaf((S), (W).y, (A).y); \
    (A).z = fmaf((S), (W).z, (A).z); \
    (A).w = fmaf((S), (W).w, (A).w); } while (0)

#define ELEM(V, I) ((I) == 0 ? (V).x : (I) == 1 ? (V).y : (I) == 2 ? (V).z : (V).w)

// Sliced node GEMM: thread = node (blockIdx.x, threadIdx.x), j-slice of 16
// output columns = blockIdx.y (SGPR -> weight addresses provably uniform ->
// s_load scalarization). Full np/BLAS chain per output element: acc=0,
// k ascending fmaf, bias AFTER (skipped entirely when null), optional relu.
// Used 3x: h1 = relu(x@W1+b1) [K=256], h = h1@W2+b2 [K=64],
//          A = h@W3[0:64]     [K=64, no bias].
__global__ __launch_bounds__(256) void gemm_slice(
    const float* __restrict__ in, int K,
    const float* __restrict__ W, const float* __restrict__ bias,
    int relu, float* __restrict__ out, int N)
{
    const int n  = blockIdx.x * 256 + threadIdx.x;
    const int jb = blockIdx.y * 16;
    if (n >= N) return;

    float4 a0 = make_float4(0.f, 0.f, 0.f, 0.f);
    float4 a1 = a0, a2 = a0, a3 = a0;

    const float4* inr = (const float4*)(in + (size_t)n * K);
    const int K4 = K >> 2;
    #pragma unroll 1
    for (int k4 = 0; k4 < K4; ++k4) {
        float4 xv = inr[k4];
        #pragma unroll
        for (int i = 0; i < 4; ++i) {
            const float s = ELEM(xv, i);
            const float4* w = (const float4*)(W + (size_t)(k4 * 4 + i) * 64 + jb);
            float4 w0 = w[0], w1 = w[1], w2 = w[2], w3 = w[3];
            FMA4(a0, s, w0); FMA4(a1, s, w1);
            FMA4(a2, s, w2); FMA4(a3, s, w3);
        }
    }

    if (bias) {   // uniform branch; skipped entirely for A (avoids +0.0 rounding edge)
        const float4* bv = (const float4*)(bias + jb);
        float4 b0 = bv[0], b1v = bv[1], b2v = bv[2], b3v = bv[3];
        a0.x += b0.x;  a0.y += b0.y;  a0.z += b0.z;  a0.w += b0.w;
        a1.x += b1v.x; a1.y += b1v.y; a1.z += b1v.z; a1.w += b1v.w;
        a2.x += b2v.x; a2.y += b2v.y; a2.z += b2v.z; a2.w += b2v.w;
        a3.x += b3v.x; a3.y += b3v.y; a3.z += b3v.z; a3.w += b3v.w;
    }
    if (relu) {
        a0.x = fmaxf(a0.x, 0.f); a0.y = fmaxf(a0.y, 0.f);
        a0.z = fmaxf(a0.z, 0.f); a0.w = fmaxf(a0.w, 0.f);
        a1.x = fmaxf(a1.x, 0.f); a1.y = fmaxf(a1.y, 0.f);
        a1.z = fmaxf(a1.z, 0.f); a1.w = fmaxf(a1.w, 0.f);
        a2.x = fmaxf(a2.x, 0.f); a2.y = fmaxf(a2.y, 0.f);
        a2.z = fmaxf(a2.z, 0.f); a2.w = fmaxf(a2.w, 0.f);
        a3.x = fmaxf(a3.x, 0.f); a3.y = fmaxf(a3.y, 0.f);
        a3.z = fmaxf(a3.z, 0.f); a3.w = fmaxf(a3.w, 0.f);
    }

    float4* g = (float4*)(out + (size_t)n * 64 + jb);
    g[0] = a0; g[1] = a1; g[2] = a2; g[3] = a3;
}

// Edge kernel: round-13 version verbatim (~104 us, near its 97 us chain
// floor). Per-thread LDS scratch (32 KB/block), Hc row staged in two 8-quad
// chunks, all 16 acc quads live through unroll-1 k-loops, np chain order.
__global__ __launch_bounds__(256, 4) void edge_kernel(
    const int* __restrict__ ei,
    const float* __restrict__ H, const float* __restrict__ A,
    const float* __restrict__ W3, const float* __restrict__ b3,
    const float* __restrict__ W4, const float* __restrict__ b4,
    float* __restrict__ out_type, float* __restrict__ out_probs, int E)
{
    __shared__ float4 HcS[256 * 8];   // 32 KB: per-thread 8-quad scratch

    const int tid = threadIdx.x;
    const int e = blockIdx.x * 256 + tid;
    const bool valid = (e < E);
    const int sw = tid & 7;
    float4* myscr = &HcS[tid * 8];

    const int c = valid ? ei[E + e] : 0;
    const int r = valid ? ei[e] : 0;
    const float4* src = (const float4*)(H + (size_t)c * 64);
    const float4* Ar  = (const float4*)(A + (size_t)r * 64);

    #pragma unroll
    for (int q = 0; q < 8; ++q) myscr[q ^ sw] = src[q];

    float4 acc[16];
    #pragma unroll
    for (int j = 0; j < 16; ++j) acc[j] = Ar[j];

    const float* W3b = W3 + 64 * 64;

    #pragma unroll 1
    for (int k4 = 0; k4 < 8; ++k4) {
        const float4 hv = myscr[k4 ^ sw];
        #pragma unroll
        for (int i = 0; i < 4; ++i) {
            const float s = ELEM(hv, i);
            const float* w = W3b + (size_t)(k4 * 4 + i) * 64;
            #pragma unroll
            for (int j = 0; j < 16; ++j) {
                float4 wv = *(const float4*)(w + 4 * j);
                FMA4(acc[j], s, wv);
            }
        }
    }

    #pragma unroll
    for (int q = 0; q < 8; ++q) myscr[q ^ sw] = src[8 + q];

    #pragma unroll 1
    for (int k4 = 8; k4 < 16; ++k4) {
        const float4 hv = myscr[(k4 - 8) ^ sw];
        #pragma unroll
        for (int i = 0; i < 4; ++i) {
            const float s = ELEM(hv, i);
            const float* w = W3b + (size_t)(k4 * 4 + i) * 64;
            #pragma unroll
            for (int j = 0; j < 16; ++j) {
                float4 wv = *(const float4*)(w + 4 * j);
                FMA4(acc[j], s, wv);
            }
        }
    }

    #pragma unroll
    for (int j = 0; j < 16; ++j) {
        float4 bv = *(const float4*)(b3 + 4 * j);
        acc[j].x = fmaxf(acc[j].x + bv.x, 0.f);
        acc[j].y = fmaxf(acc[j].y + bv.y, 0.f);
        acc[j].z = fmaxf(acc[j].z + bv.z, 0.f);
        acc[j].w = fmaxf(acc[j].w + bv.w, 0.f);
    }

    float lg[NUM_REL];
    #pragma unroll
    for (int j = 0; j < NUM_REL; ++j) lg[j] = 0.0f;
    #pragma unroll
    for (int jq = 0; jq < 16; ++jq) {
        #pragma unroll
        for (int i = 0; i < 4; ++i) {
            const float s = ELEM(acc[jq], i);
            const float* w = W4 + (size_t)(jq * 4 + i) * NUM_REL;
            #pragma unroll
            for (int j = 0; j < NUM_REL; ++j) lg[j] = fmaf(s, w[j], lg[j]);
        }
    }

    if (!valid) return;

    #pragma unroll
    for (int j = 0; j < NUM_REL; ++j) lg[j] += b4[j];

    int best = 0;
    float bm = lg[0];
    #pragma unroll
    for (int j = 1; j < NUM_REL; ++j)
        if (lg[j] > bm) { bm = lg[j]; best = j; }

    float p[NUM_REL];
    float sum = 0.0f;
    #pragma unroll
    for (int j = 0; j < NUM_REL; ++j) {
        p[j] = expf(lg[j] - bm);
        sum += p[j];
    }
    float inv = 1.0f / sum;

    out_type[e] = (float)best;
    float* op = out_probs + (size_t)e * NUM_REL;
    #pragma unroll
    for (int j = 0; j < NUM_REL; ++j) op[j] = p[j] * inv;
}

extern "C" void kernel_launch(void* const* d_in, const int* in_sizes, int n_in,
                              void* d_out, int out_size, void* d_ws, size_t ws_size,
                              hipStream_t stream)
{
    const float* x  = (const float*)d_in[0];
    const int*   ei = (const int*)d_in[1];
    const float* W1 = (const float*)d_in[2];
    const float* b1 = (const float*)d_in[3];
    const float* W2 = (const float*)d_in[4];
    const float* b2 = (const float*)d_in[5];
    const float* W3 = (const float*)d_in[6];
    const float* b3 = (const float*)d_in[7];
    const float* W4 = (const float*)d_in[8];
    const float* b4 = (const float*)d_in[9];

    int N = in_sizes[0] / NODE_DIM;   // 100000
    int E = in_sizes[1] / 2;          // 1600000

    // ws: H [N*64] | A [N*64] | H1 [N*64]  (76.8 MB; round-1 proved ws fits)
    float* H  = (float*)d_ws;
    float* A  = H + (size_t)N * 64;
    float* H1 = H + 2 * (size_t)N * 64;

    int nb = (N + 255) / 256;
    int eb = (E + 255) / 256;
    dim3 ngrid(nb, 4);

    float* out_type  = (float*)d_out;
    float* out_probs = (float*)d_out + E;

    hipLaunchKernelGGL(gemm_slice, ngrid, dim3(256), 0, stream,
                       x, NODE_DIM, W1, b1, 1, H1, N);
    hipLaunchKernelGGL(gemm_slice, ngrid, dim3(256), 0, stream,
                       H1, HIDDEN, W2, b2, 0, H, N);
    hipLaunchKernelGGL(gemm_slice, ngrid, dim3(256), 0, stream,
                       H, HIDDEN, W3, (const float*)nullptr, 0, A, N);
    hipLaunchKernelGGL(edge_kernel, dim3(eb), dim3(256), 0, stream,
                       ei, H, A, W3, b3, W4, b4, out_type, out_probs, E);
}

// Round 16
// 407.543 us; speedup vs baseline: 2.0675x; 2.0675x over previous
//
#include <hip/hip_runtime.h>

#define NODE_DIM 256
#define HIDDEN 64
#define NUM_REL 10

#define FMA4(A, S, W) do { \
    (A).x = fmaf((S), (W).x, (A).x); \
    (A).y = fmaf((S), (W).y, (A).y); \
    (A).z = fmaf((S), (W).z, (A).z); \
    (A).w = fmaf((S), (W).w, (A).w); } while (0)

#define ELEM(V, I) ((I) == 0 ? (V).x : (I) == 1 ? (V).y : (I) == 2 ? (V).z : (V).w)

// Node kernel = R5 form (64 scalar accumulators, VGPR~100, wave-uniform W ->
// s_load path) with ONE change: L1's x-row reads go through cooperative,
// coalesced LDS staging (32-k chunks; 8-lane groups load 128B contiguous;
// row stride 33 floats -> scalar reads conflict-free, writes <=2-way=free).
// Chain per output element unchanged: acc=0, k ascending fmaf, bias AFTER,
// relu -> bit-identical to rounds 5-15.
__global__ __launch_bounds__(256, 4) void node_kernel(
    const float* __restrict__ x,
    const float* __restrict__ W1, const float* __restrict__ b1,
    const float* __restrict__ W2, const float* __restrict__ b2,
    const float* __restrict__ W3,
    float* __restrict__ Hout, float* __restrict__ Aout, int N)
{
    __shared__ float xs[256 * 33];       // 33.8 KB

    const int tid   = threadIdx.x;
    const int n     = blockIdx.x * 256 + tid;
    const bool valid = (n < N);
    const int rbase = blockIdx.x * 256;
    const int myq   = tid & 7;           // quad within the 32-float chunk
    const int r0    = tid >> 3;          // base row this thread stages

    // ---- L1: h1 = relu((x@W1) + b1), x staged chunk-wise ----
    float h1[64];
    #pragma unroll
    for (int j = 0; j < 64; ++j) h1[j] = 0.0f;

    #pragma unroll 1
    for (int c = 0; c < 8; ++c) {
        __syncthreads();                 // previous chunk fully consumed
        #pragma unroll
        for (int i = 0; i < 8; ++i) {
            const int row  = r0 + 32 * i;
            const int node = rbase + row;
            const int nodec = (node < N) ? node : (N - 1);
            float4 v = *(const float4*)(x + (size_t)nodec * NODE_DIM
                                          + c * 32 + myq * 4);
            float* d = &xs[row * 33 + myq * 4];
            d[0] = v.x; d[1] = v.y; d[2] = v.z; d[3] = v.w;
        }
        __syncthreads();

        const float* myrow = &xs[tid * 33];
        #pragma unroll 1
        for (int k4 = 0; k4 < 8; ++k4) {
            const float s0 = myrow[k4 * 4 + 0];
            const float s1 = myrow[k4 * 4 + 1];
            const float s2 = myrow[k4 * 4 + 2];
            const float s3 = myrow[k4 * 4 + 3];
            const float* w = W1 + (size_t)(c * 32 + k4 * 4) * 64;
            #pragma unroll
            for (int j = 0; j < 64; ++j) h1[j] = fmaf(s0, w[j], h1[j]);
            #pragma unroll
            for (int j = 0; j < 64; ++j) h1[j] = fmaf(s1, w[64 + j], h1[j]);
            #pragma unroll
            for (int j = 0; j < 64; ++j) h1[j] = fmaf(s2, w[128 + j], h1[j]);
            #pragma unroll
            for (int j = 0; j < 64; ++j) h1[j] = fmaf(s3, w[192 + j], h1[j]);
        }
    }
    #pragma unroll
    for (int j = 0; j < 64; ++j) h1[j] = fmaxf(h1[j] + b1[j], 0.0f);

    // ---- L2: h = (h1@W2) + b2  (R5 verbatim) ----
    float h[64];
    #pragma unroll
    for (int c = 0; c < 4; ++c) {
        float acc[16];
        #pragma unroll
        for (int j = 0; j < 16; ++j) acc[j] = 0.0f;
        #pragma unroll
        for (int k = 0; k < 64; ++k) {
            const float* w = W2 + (size_t)k * 64 + c * 16;
            #pragma unroll
            for (int j = 0; j < 16; ++j) acc[j] = fmaf(h1[k], w[j], acc[j]);
        }
        #pragma unroll
        for (int j = 0; j < 16; ++j) h[c * 16 + j] = acc[j] + b2[c * 16 + j];
    }

    if (valid) {
        float4* hr = (float4*)(Hout + (size_t)n * 64);
        #pragma unroll
        for (int j4 = 0; j4 < 16; ++j4) {
            float4 v;
            v.x = h[4 * j4]; v.y = h[4 * j4 + 1];
            v.z = h[4 * j4 + 2]; v.w = h[4 * j4 + 3];
            hr[j4] = v;
        }
    }

    // ---- L3 row-half partial: A = h @ W3[0:64], no bias (R5 verbatim) ----
    #pragma unroll
    for (int c = 0; c < 4; ++c) {
        float acc[16];
        #pragma unroll
        for (int j = 0; j < 16; ++j) acc[j] = 0.0f;
        #pragma unroll
        for (int k = 0; k < 64; ++k) {
            const float* w = W3 + (size_t)k * 64 + c * 16;
            #pragma unroll
            for (int j = 0; j < 16; ++j) acc[j] = fmaf(h[k], w[j], acc[j]);
        }
        if (valid) {
            float4* ar = (float4*)(Aout + (size_t)n * 64);
            #pragma unroll
            for (int j4 = 0; j4 < 4; ++j4) {
                float4 v;
                v.x = acc[4 * j4]; v.y = acc[4 * j4 + 1];
                v.z = acc[4 * j4 + 2]; v.w = acc[4 * j4 + 3];
                ar[c * 4 + j4] = v;
            }
        }
    }
}

// Edge kernel: round-13 version verbatim (~100-104 us, near its 97 us chain
// floor). Per-thread LDS scratch (32 KB/block), Hc row staged in two 8-quad
// chunks, all 16 acc quads live through unroll-1 k-loops, np chain order.
__global__ __launch_bounds__(256, 4) void edge_kernel(
    const int* __restrict__ ei,
    const float* __restrict__ H, const float* __restrict__ A,
    const float* __restrict__ W3, const float* __restrict__ b3,
    const float* __restrict__ W4, const float* __restrict__ b4,
    float* __restrict__ out_type, float* __restrict__ out_probs, int E)
{
    __shared__ float4 HcS[256 * 8];   // 32 KB: per-thread 8-quad scratch

    const int tid = threadIdx.x;
    const int e = blockIdx.x * 256 + tid;
    const bool valid = (e < E);
    const int sw = tid & 7;
    float4* myscr = &HcS[tid * 8];

    const int c = valid ? ei[E + e] : 0;
    const int r = valid ? ei[e] : 0;
    const float4* src = (const float4*)(H + (size_t)c * 64);
    const float4* Ar  = (const float4*)(A + (size_t)r * 64);

    #pragma unroll
    for (int q = 0; q < 8; ++q) myscr[q ^ sw] = src[q];

    float4 acc[16];
    #pragma unroll
    for (int j = 0; j < 16; ++j) acc[j] = Ar[j];

    const float* W3b = W3 + 64 * 64;

    #pragma unroll 1
    for (int k4 = 0; k4 < 8; ++k4) {
        const float4 hv = myscr[k4 ^ sw];
        #pragma unroll
        for (int i = 0; i < 4; ++i) {
            const float s = ELEM(hv, i);
            const float* w = W3b + (size_t)(k4 * 4 + i) * 64;
            #pragma unroll
            for (int j = 0; j < 16; ++j) {
                float4 wv = *(const float4*)(w + 4 * j);
                FMA4(acc[j], s, wv);
            }
        }
    }

    #pragma unroll
    for (int q = 0; q < 8; ++q) myscr[q ^ sw] = src[8 + q];

    #pragma unroll 1
    for (int k4 = 8; k4 < 16; ++k4) {
        const float4 hv = myscr[(k4 - 8) ^ sw];
        #pragma unroll
        for (int i = 0; i < 4; ++i) {
            const float s = ELEM(hv, i);
            const float* w = W3b + (size_t)(k4 * 4 + i) * 64;
            #pragma unroll
            for (int j = 0; j < 16; ++j) {
                float4 wv = *(const float4*)(w + 4 * j);
                FMA4(acc[j], s, wv);
            }
        }
    }

    #pragma unroll
    for (int j = 0; j < 16; ++j) {
        float4 bv = *(const float4*)(b3 + 4 * j);
        acc[j].x = fmaxf(acc[j].x + bv.x, 0.f);
        acc[j].y = fmaxf(acc[j].y + bv.y, 0.f);
        acc[j].z = fmaxf(acc[j].z + bv.z, 0.f);
        acc[j].w = fmaxf(acc[j].w + bv.w, 0.f);
    }

    float lg[NUM_REL];
    #pragma unroll
    for (int j = 0; j < NUM_REL; ++j) lg[j] = 0.0f;
    #pragma unroll
    for (int jq = 0; jq < 16; ++jq) {
        #pragma unroll
        for (int i = 0; i < 4; ++i) {
            const float s = ELEM(acc[jq], i);
            const float* w = W4 + (size_t)(jq * 4 + i) * NUM_REL;
            #pragma unroll
            for (int j = 0; j < NUM_REL; ++j) lg[j] = fmaf(s, w[j], lg[j]);
        }
    }

    if (!valid) return;

    #pragma unroll
    for (int j = 0; j < NUM_REL; ++j) lg[j] += b4[j];

    int best = 0;
    float bm = lg[0];
    #pragma unroll
    for (int j = 1; j < NUM_REL; ++j)
        if (lg[j] > bm) { bm = lg[j]; best = j; }

    float p[NUM_REL];
    float sum = 0.0f;
    #pragma unroll
    for (int j = 0; j < NUM_REL; ++j) {
        p[j] = expf(lg[j] - bm);
        sum += p[j];
    }
    float inv = 1.0f / sum;

    out_type[e] = (float)best;
    float* op = out_probs + (size_t)e * NUM_REL;
    #pragma unroll
    for (int j = 0; j < NUM_REL; ++j) op[j] = p[j] * inv;
}

extern "C" void kernel_launch(void* const* d_in, const int* in_sizes, int n_in,
                              void* d_out, int out_size, void* d_ws, size_t ws_size,
                              hipStream_t stream)
{
    const float* x  = (const float*)d_in[0];
    const int*   ei = (const int*)d_in[1];
    const float* W1 = (const float*)d_in[2];
    const float* b1 = (const float*)d_in[3];
    const float* W2 = (const float*)d_in[4];
    const float* b2 = (const float*)d_in[5];
    const float* W3 = (const float*)d_in[6];
    const float* b3 = (const float*)d_in[7];
    const float* W4 = (const float*)d_in[8];
    const float* b4 = (const float*)d_in[9];

    int N = in_sizes[0] / NODE_DIM;   // 100000
    int E = in_sizes[1] / 2;          // 1600000

    // ws: H [N*64] f32 | A [N*64] f32   (51.2 MB total)
    float* H = (float*)d_ws;
    float* A = H + (size_t)N * 64;

    int nb = (N + 255) / 256;
    int eb = (E + 255) / 256;

    float* out_type  = (float*)d_out;
    float* out_probs = (float*)d_out + E;

    hipLaunchKernelGGL(node_kernel, dim3(nb), dim3(256), 0, stream,
                       x, W1, b1, W2, b2, W3, H, A, N);
    hipLaunchKernelGGL(edge_kernel, dim3(eb), dim3(256), 0, stream,
                       ei, H, A, W3, b3, W4, b4, out_type, out_probs, E);
}

// Round 17
// 308.098 us; speedup vs baseline: 2.7349x; 1.3228x over previous
//
#include <hip/hip_runtime.h>

#define NODE_DIM 256
#define HIDDEN 64
#define NUM_REL 10

#define FMA4(A, S, W) do { \
    (A).x = fmaf((S), (W).x, (A).x); \
    (A).y = fmaf((S), (W).y, (A).y); \
    (A).z = fmaf((S), (W).z, (A).z); \
    (A).w = fmaf((S), (W).w, (A).w); } while (0)

#define ELEM(V, I) ((I) == 0 ? (V).x : (I) == 1 ? (V).y : (I) == 2 ? (V).z : (V).w)

// Node pipeline: block = 4 waves x 64 lanes; lane = node, wave = j-slice.
// KEY FIX vs R14: jb goes through readfirstlane -> SGPR -> weight/bias
// addresses provably wave-uniform -> s_load scalarization (R8/R14 failure
// mode eliminated). h1/h handed between layers via LDS [64][65] (write
// (l+jb+i)%32 distinct per lane; read scalar per-lane row -> conflict-free).
// Per-element np/BLAS chain unchanged: acc=0, k ascending fmaf over FULL K,
// bias AFTER, relu -> bit-identical to rounds 5-16.
__global__ __launch_bounds__(256, 4) void node_kernel(
    const float* __restrict__ x,
    const float* __restrict__ W1, const float* __restrict__ b1,
    const float* __restrict__ W2, const float* __restrict__ b2,
    const float* __restrict__ W3,
    float* __restrict__ Hout, float* __restrict__ Aout, int N)
{
    __shared__ float h1s[64][65];
    __shared__ float hs[64][65];

    const int tid  = threadIdx.x;
    const int lane = tid & 63;                  // node within tile
    const int jb   = __builtin_amdgcn_readfirstlane((tid >> 6) << 4); // SGPR j-base
    const int n    = blockIdx.x * 64 + lane;
    const bool valid = (n < N);
    const int nc   = valid ? n : (N - 1);

    // ---- L1 slice: h1[jb..jb+16) = relu((x@W1) + b1) ----
    float4 a0 = make_float4(0.f, 0.f, 0.f, 0.f);
    float4 a1 = a0, a2 = a0, a3 = a0;

    const float4* xr = (const float4*)(x + (size_t)nc * NODE_DIM);
    #pragma unroll 1
    for (int k4 = 0; k4 < NODE_DIM / 4; ++k4) {
        float4 xv = xr[k4];
        #pragma unroll
        for (int i = 0; i < 4; ++i) {
            const float s = ELEM(xv, i);
            const float4* w = (const float4*)(W1 + (size_t)(k4 * 4 + i) * 64 + jb);
            float4 w0 = w[0], w1 = w[1], w2 = w[2], w3 = w[3];
            FMA4(a0, s, w0); FMA4(a1, s, w1);
            FMA4(a2, s, w2); FMA4(a3, s, w3);
        }
    }
    {
        const float4* bv = (const float4*)(b1 + jb);
        float4 b0 = bv[0], b1v = bv[1], b2v = bv[2], b3v = bv[3];
        float* d = &h1s[lane][jb];
        d[0]  = fmaxf(a0.x + b0.x, 0.f);  d[1]  = fmaxf(a0.y + b0.y, 0.f);
        d[2]  = fmaxf(a0.z + b0.z, 0.f);  d[3]  = fmaxf(a0.w + b0.w, 0.f);
        d[4]  = fmaxf(a1.x + b1v.x, 0.f); d[5]  = fmaxf(a1.y + b1v.y, 0.f);
        d[6]  = fmaxf(a1.z + b1v.z, 0.f); d[7]  = fmaxf(a1.w + b1v.w, 0.f);
        d[8]  = fmaxf(a2.x + b2v.x, 0.f); d[9]  = fmaxf(a2.y + b2v.y, 0.f);
        d[10] = fmaxf(a2.z + b2v.z, 0.f); d[11] = fmaxf(a2.w + b2v.w, 0.f);
        d[12] = fmaxf(a3.x + b3v.x, 0.f); d[13] = fmaxf(a3.y + b3v.y, 0.f);
        d[14] = fmaxf(a3.z + b3v.z, 0.f); d[15] = fmaxf(a3.w + b3v.w, 0.f);
    }
    __syncthreads();

    // ---- L2 slice: h[jb..jb+16) = (h1@W2) + b2 ----
    a0 = make_float4(0.f, 0.f, 0.f, 0.f); a1 = a0; a2 = a0; a3 = a0;
    #pragma unroll 1
    for (int k = 0; k < 64; ++k) {
        const float s = h1s[lane][k];
        const float4* w = (const float4*)(W2 + (size_t)k * 64 + jb);
        float4 w0 = w[0], w1 = w[1], w2 = w[2], w3 = w[3];
        FMA4(a0, s, w0); FMA4(a1, s, w1);
        FMA4(a2, s, w2); FMA4(a3, s, w3);
    }
    {
        const float4* bv = (const float4*)(b2 + jb);
        float4 b0 = bv[0], b1v = bv[1], b2v = bv[2], b3v = bv[3];
        float4 r0, r1, r2, r3;
        r0.x = a0.x + b0.x;  r0.y = a0.y + b0.y;  r0.z = a0.z + b0.z;  r0.w = a0.w + b0.w;
        r1.x = a1.x + b1v.x; r1.y = a1.y + b1v.y; r1.z = a1.z + b1v.z; r1.w = a1.w + b1v.w;
        r2.x = a2.x + b2v.x; r2.y = a2.y + b2v.y; r2.z = a2.z + b2v.z; r2.w = a2.w + b2v.w;
        r3.x = a3.x + b3v.x; r3.y = a3.y + b3v.y; r3.z = a3.z + b3v.z; r3.w = a3.w + b3v.w;
        float* d = &hs[lane][jb];
        d[0]  = r0.x; d[1]  = r0.y; d[2]  = r0.z; d[3]  = r0.w;
        d[4]  = r1.x; d[5]  = r1.y; d[6]  = r1.z; d[7]  = r1.w;
        d[8]  = r2.x; d[9]  = r2.y; d[10] = r2.z; d[11] = r2.w;
        d[12] = r3.x; d[13] = r3.y; d[14] = r3.z; d[15] = r3.w;
        if (valid) {
            float4* g = (float4*)(Hout + (size_t)n * 64 + jb);
            g[0] = r0; g[1] = r1; g[2] = r2; g[3] = r3;
        }
    }
    __syncthreads();

    // ---- L3 row-half partial slice: A[jb..jb+16) = h @ W3[0:64], no bias ----
    a0 = make_float4(0.f, 0.f, 0.f, 0.f); a1 = a0; a2 = a0; a3 = a0;
    #pragma unroll 1
    for (int k = 0; k < 64; ++k) {
        const float s = hs[lane][k];
        const float4* w = (const float4*)(W3 + (size_t)k * 64 + jb);
        float4 w0 = w[0], w1 = w[1], w2 = w[2], w3 = w[3];
        FMA4(a0, s, w0); FMA4(a1, s, w1);
        FMA4(a2, s, w2); FMA4(a3, s, w3);
    }
    if (valid) {
        float4* g = (float4*)(Aout + (size_t)n * 64 + jb);
        g[0] = a0; g[1] = a1; g[2] = a2; g[3] = a3;
    }
}

// Edge kernel: round-13 version verbatim (~100-104 us, near its 97 us chain
// floor). Per-thread LDS scratch (32 KB/block), Hc row staged in two 8-quad
// chunks, all 16 acc quads live through unroll-1 k-loops, np chain order.
__global__ __launch_bounds__(256, 4) void edge_kernel(
    const int* __restrict__ ei,
    const float* __restrict__ H, const float* __restrict__ A,
    const float* __restrict__ W3, const float* __restrict__ b3,
    const float* __restrict__ W4, const float* __restrict__ b4,
    float* __restrict__ out_type, float* __restrict__ out_probs, int E)
{
    __shared__ float4 HcS[256 * 8];   // 32 KB: per-thread 8-quad scratch

    const int tid = threadIdx.x;
    const int e = blockIdx.x * 256 + tid;
    const bool valid = (e < E);
    const int sw = tid & 7;
    float4* myscr = &HcS[tid * 8];

    const int c = valid ? ei[E + e] : 0;
    const int r = valid ? ei[e] : 0;
    const float4* src = (const float4*)(H + (size_t)c * 64);
    const float4* Ar  = (const float4*)(A + (size_t)r * 64);

    #pragma unroll
    for (int q = 0; q < 8; ++q) myscr[q ^ sw] = src[q];

    float4 acc[16];
    #pragma unroll
    for (int j = 0; j < 16; ++j) acc[j] = Ar[j];

    const float* W3b = W3 + 64 * 64;

    #pragma unroll 1
    for (int k4 = 0; k4 < 8; ++k4) {
        const float4 hv = myscr[k4 ^ sw];
        #pragma unroll
        for (int i = 0; i < 4; ++i) {
            const float s = ELEM(hv, i);
            const float* w = W3b + (size_t)(k4 * 4 + i) * 64;
            #pragma unroll
            for (int j = 0; j < 16; ++j) {
                float4 wv = *(const float4*)(w + 4 * j);
                FMA4(acc[j], s, wv);
            }
        }
    }

    #pragma unroll
    for (int q = 0; q < 8; ++q) myscr[q ^ sw] = src[8 + q];

    #pragma unroll 1
    for (int k4 = 8; k4 < 16; ++k4) {
        const float4 hv = myscr[(k4 - 8) ^ sw];
        #pragma unroll
        for (int i = 0; i < 4; ++i) {
            const float s = ELEM(hv, i);
            const float* w = W3b + (size_t)(k4 * 4 + i) * 64;
            #pragma unroll
            for (int j = 0; j < 16; ++j) {
                float4 wv = *(const float4*)(w + 4 * j);
                FMA4(acc[j], s, wv);
            }
        }
    }

    #pragma unroll
    for (int j = 0; j < 16; ++j) {
        float4 bv = *(const float4*)(b3 + 4 * j);
        acc[j].x = fmaxf(acc[j].x + bv.x, 0.f);
        acc[j].y = fmaxf(acc[j].y + bv.y, 0.f);
        acc[j].z = fmaxf(acc[j].z + bv.z, 0.f);
        acc[j].w = fmaxf(acc[j].w + bv.w, 0.f);
    }

    float lg[NUM_REL];
    #pragma unroll
    for (int j = 0; j < NUM_REL; ++j) lg[j] = 0.0f;
    #pragma unroll
    for (int jq = 0; jq < 16; ++jq) {
        #pragma unroll
        for (int i = 0; i < 4; ++i) {
            const float s = ELEM(acc[jq], i);
            const float* w = W4 + (size_t)(jq * 4 + i) * NUM_REL;
            #pragma unroll
            for (int j = 0; j < NUM_REL; ++j) lg[j] = fmaf(s, w[j], lg[j]);
        }
    }

    if (!valid) return;

    #pragma unroll
    for (int j = 0; j < NUM_REL; ++j) lg[j] += b4[j];

    int best = 0;
    float bm = lg[0];
    #pragma unroll
    for (int j = 1; j < NUM_REL; ++j)
        if (lg[j] > bm) { bm = lg[j]; best = j; }

    float p[NUM_REL];
    float sum = 0.0f;
    #pragma unroll
    for (int j = 0; j < NUM_REL; ++j) {
        p[j] = expf(lg[j] - bm);
        sum += p[j];
    }
    float inv = 1.0f / sum;

    out_type[e] = (float)best;
    float* op = out_probs + (size_t)e * NUM_REL;
    #pragma unroll
    for (int j = 0; j < NUM_REL; ++j) op[j] = p[j] * inv;
}

extern "C" void kernel_launch(void* const* d_in, const int* in_sizes, int n_in,
                              void* d_out, int out_size, void* d_ws, size_t ws_size,
                              hipStream_t stream)
{
    const float* x  = (const float*)d_in[0];
    const int*   ei = (const int*)d_in[1];
    const float* W1 = (const float*)d_in[2];
    const float* b1 = (const float*)d_in[3];
    const float* W2 = (const float*)d_in[4];
    const float* b2 = (const float*)d_in[5];
    const float* W3 = (const float*)d_in[6];
    const float* b3 = (const float*)d_in[7];
    const float* W4 = (const float*)d_in[8];
    const float* b4 = (const float*)d_in[9];

    int N = in_sizes[0] / NODE_DIM;   // 100000
    int E = in_sizes[1] / 2;          // 1600000

    // ws: H [N*64] f32 | A [N*64] f32   (51.2 MB total)
    float* H = (float*)d_ws;
    float* A = H + (size_t)N * 64;

    int nb = (N + 63) / 64;
    int eb = (E + 255) / 256;

    float* out_type  = (float*)d_out;
    float* out_probs = (float*)d_out + E;

    hipLaunchKernelGGL(node_kernel, dim3(nb), dim3(256), 0, stream,
                       x, W1, b1, W2, b2, W3, H, A, N);
    hipLaunchKernelGGL(edge_kernel, dim3(eb), dim3(256), 0, stream,
                       ei, H, A, W3, b3, W4, b4, out_type, out_probs, E);
}

// Round 18
// 307.828 us; speedup vs baseline: 2.7373x; 1.0009x over previous
//
#include <hip/hip_runtime.h>

#define NODE_DIM 256
#define HIDDEN 64
#define NUM_REL 10

#define FMA4(A, S, W) do { \
    (A).x = fmaf((S), (W).x, (A).x); \
    (A).y = fmaf((S), (W).y, (A).y); \
    (A).z = fmaf((S), (W).z, (A).z); \
    (A).w = fmaf((S), (W).w, (A).w); } while (0)

#define ELEM(V, I) ((I) == 0 ? (V).x : (I) == 1 ? (V).y : (I) == 2 ? (V).z : (V).w)
#define LD4(P, O) (*(const float4*)((P) + (O)))

// FMA into all 16 named accumulators (j ascending): the accumulator set is
// 16 NAMED variables, not an array -> nothing to strip-mine or AGPR-bounce.
#define ALLFMA(S, W) do { \
    FMA4(c0,(S),LD4(W,0));   FMA4(c1,(S),LD4(W,4));   \
    FMA4(c2,(S),LD4(W,8));   FMA4(c3,(S),LD4(W,12));  \
    FMA4(c4,(S),LD4(W,16));  FMA4(c5,(S),LD4(W,20));  \
    FMA4(c6,(S),LD4(W,24));  FMA4(c7,(S),LD4(W,28));  \
    FMA4(c8,(S),LD4(W,32));  FMA4(c9,(S),LD4(W,36));  \
    FMA4(c10,(S),LD4(W,40)); FMA4(c11,(S),LD4(W,44)); \
    FMA4(c12,(S),LD4(W,48)); FMA4(c13,(S),LD4(W,52)); \
    FMA4(c14,(S),LD4(W,56)); FMA4(c15,(S),LD4(W,60)); } while (0)

#define BRELU(C, JQ) do { \
    float4 bv = LD4(b3, 4 * (JQ)); \
    (C).x = fmaxf((C).x + bv.x, 0.f); (C).y = fmaxf((C).y + bv.y, 0.f); \
    (C).z = fmaxf((C).z + bv.z, 0.f); (C).w = fmaxf((C).w + bv.w, 0.f); } while (0)

#define LOGIT4(C, JQ) do { \
    _Pragma("unroll") \
    for (int i = 0; i < 4; ++i) { \
        const float s = ELEM((C), i); \
        const float* wp = W4 + (size_t)((JQ) * 4 + i) * NUM_REL; \
        _Pragma("unroll") \
        for (int j = 0; j < NUM_REL; ++j) lg[j] = fmaf(s, wp[j], lg[j]); \
    } } while (0)

// Edge kernel (compiled FIRST to isolate regalloc from node_kernel — R17's
// 104->214us regression was co-compilation codegen drift, rule #19).
// Structure = R13: per-thread LDS scratch (32 KB/block), Hc row staged in two
// 8-quad chunks, 16 NAMED acc quads live through unroll-1 k-loops, np chain
// order (k ascending over W3 rows 64..127, +b3 after, relu, j-ascending
// logits, +b4) -> bit-identical output.
__global__ __launch_bounds__(256, 4) void edge_kernel(
    const int* __restrict__ ei,
    const float* __restrict__ H, const float* __restrict__ A,
    const float* __restrict__ W3, const float* __restrict__ b3,
    const float* __restrict__ W4, const float* __restrict__ b4,
    float* __restrict__ out_type, float* __restrict__ out_probs, int E)
{
    __shared__ float4 HcS[256 * 8];   // 32 KB: per-thread 8-quad scratch

    const int tid = threadIdx.x;
    const int e = blockIdx.x * 256 + tid;
    const bool valid = (e < E);
    const int sw = tid & 7;
    float4* myscr = &HcS[tid * 8];

    const int c = valid ? ei[E + e] : 0;
    const int r = valid ? ei[e] : 0;
    const float4* src = (const float4*)(H + (size_t)c * 64);
    const float4* Ar  = (const float4*)(A + (size_t)r * 64);

    #pragma unroll
    for (int q = 0; q < 8; ++q) myscr[q ^ sw] = src[q];

    float4 c0 = Ar[0],  c1 = Ar[1],  c2 = Ar[2],  c3 = Ar[3];
    float4 c4 = Ar[4],  c5 = Ar[5],  c6 = Ar[6],  c7 = Ar[7];
    float4 c8 = Ar[8],  c9 = Ar[9],  c10 = Ar[10], c11 = Ar[11];
    float4 c12 = Ar[12], c13 = Ar[13], c14 = Ar[14], c15 = Ar[15];

    const float* W3b = W3 + 64 * 64;

    #pragma unroll 1
    for (int k4 = 0; k4 < 8; ++k4) {
        const float4 hv = myscr[k4 ^ sw];
        #pragma unroll
        for (int i = 0; i < 4; ++i) {
            const float s = ELEM(hv, i);
            const float* w = W3b + (size_t)(k4 * 4 + i) * 64;
            ALLFMA(s, w);
        }
    }

    #pragma unroll
    for (int q = 0; q < 8; ++q) myscr[q ^ sw] = src[8 + q];

    #pragma unroll 1
    for (int k4 = 8; k4 < 16; ++k4) {
        const float4 hv = myscr[(k4 - 8) ^ sw];
        #pragma unroll
        for (int i = 0; i < 4; ++i) {
            const float s = ELEM(hv, i);
            const float* w = W3b + (size_t)(k4 * 4 + i) * 64;
            ALLFMA(s, w);
        }
    }

    BRELU(c0, 0);   BRELU(c1, 1);   BRELU(c2, 2);   BRELU(c3, 3);
    BRELU(c4, 4);   BRELU(c5, 5);   BRELU(c6, 6);   BRELU(c7, 7);
    BRELU(c8, 8);   BRELU(c9, 9);   BRELU(c10, 10); BRELU(c11, 11);
    BRELU(c12, 12); BRELU(c13, 13); BRELU(c14, 14); BRELU(c15, 15);

    float lg[NUM_REL];
    #pragma unroll
    for (int j = 0; j < NUM_REL; ++j) lg[j] = 0.0f;
    LOGIT4(c0, 0);   LOGIT4(c1, 1);   LOGIT4(c2, 2);   LOGIT4(c3, 3);
    LOGIT4(c4, 4);   LOGIT4(c5, 5);   LOGIT4(c6, 6);   LOGIT4(c7, 7);
    LOGIT4(c8, 8);   LOGIT4(c9, 9);   LOGIT4(c10, 10); LOGIT4(c11, 11);
    LOGIT4(c12, 12); LOGIT4(c13, 13); LOGIT4(c14, 14); LOGIT4(c15, 15);

    if (!valid) return;

    #pragma unroll
    for (int j = 0; j < NUM_REL; ++j) lg[j] += b4[j];

    int best = 0;
    float bm = lg[0];
    #pragma unroll
    for (int j = 1; j < NUM_REL; ++j)
        if (lg[j] > bm) { bm = lg[j]; best = j; }

    float p[NUM_REL];
    float sum = 0.0f;
    #pragma unroll
    for (int j = 0; j < NUM_REL; ++j) {
        p[j] = expf(lg[j] - bm);
        sum += p[j];
    }
    float inv = 1.0f / sum;

    out_type[e] = (float)best;
    float* op = out_probs + (size_t)e * NUM_REL;
    #pragma unroll
    for (int j = 0; j < NUM_REL; ++j) op[j] = p[j] * inv;
}

// Node pipeline: R17 verbatim (~94 us). Block = 4 waves x 64 lanes; lane =
// node, wave = j-slice via readfirstlane -> SGPR -> s_load weights. h1/h
// handed between layers via LDS [64][65]. Per-element np/BLAS chain: acc=0,
// k ascending fmaf over FULL K, bias AFTER, relu -> bit-identical.
__global__ __launch_bounds__(256, 4) void node_kernel(
    const float* __restrict__ x,
    const float* __restrict__ W1, const float* __restrict__ b1,
    const float* __restrict__ W2, const float* __restrict__ b2,
    const float* __restrict__ W3,
    float* __restrict__ Hout, float* __restrict__ Aout, int N)
{
    __shared__ float h1s[64][65];
    __shared__ float hs[64][65];

    const int tid  = threadIdx.x;
    const int lane = tid & 63;
    const int jb   = __builtin_amdgcn_readfirstlane((tid >> 6) << 4);
    const int n    = blockIdx.x * 64 + lane;
    const bool valid = (n < N);
    const int nc   = valid ? n : (N - 1);

    // ---- L1 slice: h1[jb..jb+16) = relu((x@W1) + b1) ----
    float4 a0 = make_float4(0.f, 0.f, 0.f, 0.f);
    float4 a1 = a0, a2 = a0, a3 = a0;

    const float4* xr = (const float4*)(x + (size_t)nc * NODE_DIM);
    #pragma unroll 1
    for (int k4 = 0; k4 < NODE_DIM / 4; ++k4) {
        float4 xv = xr[k4];
        #pragma unroll
        for (int i = 0; i < 4; ++i) {
            const float s = ELEM(xv, i);
            const float4* w = (const float4*)(W1 + (size_t)(k4 * 4 + i) * 64 + jb);
            float4 w0 = w[0], w1 = w[1], w2 = w[2], w3 = w[3];
            FMA4(a0, s, w0); FMA4(a1, s, w1);
            FMA4(a2, s, w2); FMA4(a3, s, w3);
        }
    }
    {
        const float4* bv = (const float4*)(b1 + jb);
        float4 b0 = bv[0], b1v = bv[1], b2v = bv[2], b3v = bv[3];
        float* d = &h1s[lane][jb];
        d[0]  = fmaxf(a0.x + b0.x, 0.f);  d[1]  = fmaxf(a0.y + b0.y, 0.f);
        d[2]  = fmaxf(a0.z + b0.z, 0.f);  d[3]  = fmaxf(a0.w + b0.w, 0.f);
        d[4]  = fmaxf(a1.x + b1v.x, 0.f); d[5]  = fmaxf(a1.y + b1v.y, 0.f);
        d[6]  = fmaxf(a1.z + b1v.z, 0.f); d[7]  = fmaxf(a1.w + b1v.w, 0.f);
        d[8]  = fmaxf(a2.x + b2v.x, 0.f); d[9]  = fmaxf(a2.y + b2v.y, 0.f);
        d[10] = fmaxf(a2.z + b2v.z, 0.f); d[11] = fmaxf(a2.w + b2v.w, 0.f);
        d[12] = fmaxf(a3.x + b3v.x, 0.f); d[13] = fmaxf(a3.y + b3v.y, 0.f);
        d[14] = fmaxf(a3.z + b3v.z, 0.f); d[15] = fmaxf(a3.w + b3v.w, 0.f);
    }
    __syncthreads();

    // ---- L2 slice: h[jb..jb+16) = (h1@W2) + b2 ----
    a0 = make_float4(0.f, 0.f, 0.f, 0.f); a1 = a0; a2 = a0; a3 = a0;
    #pragma unroll 1
    for (int k = 0; k < 64; ++k) {
        const float s = h1s[lane][k];
        const float4* w = (const float4*)(W2 + (size_t)k * 64 + jb);
        float4 w0 = w[0], w1 = w[1], w2 = w[2], w3 = w[3];
        FMA4(a0, s, w0); FMA4(a1, s, w1);
        FMA4(a2, s, w2); FMA4(a3, s, w3);
    }
    {
        const float4* bv = (const float4*)(b2 + jb);
        float4 b0 = bv[0], b1v = bv[1], b2v = bv[2], b3v = bv[3];
        float4 r0, r1, r2, r3;
        r0.x = a0.x + b0.x;  r0.y = a0.y + b0.y;  r0.z = a0.z + b0.z;  r0.w = a0.w + b0.w;
        r1.x = a1.x + b1v.x; r1.y = a1.y + b1v.y; r1.z = a1.z + b1v.z; r1.w = a1.w + b1v.w;
        r2.x = a2.x + b2v.x; r2.y = a2.y + b2v.y; r2.z = a2.z + b2v.z; r2.w = a2.w + b2v.w;
        r3.x = a3.x + b3v.x; r3.y = a3.y + b3v.y; r3.z = a3.z + b3v.z; r3.w = a3.w + b3v.w;
        float* d = &hs[lane][jb];
        d[0]  = r0.x; d[1]  = r0.y; d[2]  = r0.z; d[3]  = r0.w;
        d[4]  = r1.x; d[5]  = r1.y; d[6]  = r1.z; d[7]  = r1.w;
        d[8]  = r2.x; d[9]  = r2.y; d[10] = r2.z; d[11] = r2.w;
        d[12] = r3.x; d[13] = r3.y; d[14] = r3.z; d[15] = r3.w;
        if (valid) {
            float4* g = (float4*)(Hout + (size_t)n * 64 + jb);
            g[0] = r0; g[1] = r1; g[2] = r2; g[3] = r3;
        }
    }
    __syncthreads();

    // ---- L3 row-half partial slice: A[jb..jb+16) = h @ W3[0:64], no bias ----
    a0 = make_float4(0.f, 0.f, 0.f, 0.f); a1 = a0; a2 = a0; a3 = a0;
    #pragma unroll 1
    for (int k = 0; k < 64; ++k) {
        const float s = hs[lane][k];
        const float4* w = (const float4*)(W3 + (size_t)k * 64 + jb);
        float4 w0 = w[0], w1 = w[1], w2 = w[2], w3 = w[3];
        FMA4(a0, s, w0); FMA4(a1, s, w1);
        FMA4(a2, s, w2); FMA4(a3, s, w3);
    }
    if (valid) {
        float4* g = (float4*)(Aout + (size_t)n * 64 + jb);
        g[0] = a0; g[1] = a1; g[2] = a2; g[3] = a3;
    }
}

extern "C" void kernel_launch(void* const* d_in, const int* in_sizes, int n_in,
                              void* d_out, int out_size, void* d_ws, size_t ws_size,
                              hipStream_t stream)
{
    const float* x  = (const float*)d_in[0];
    const int*   ei = (const int*)d_in[1];
    const float* W1 = (const float*)d_in[2];
    const float* b1 = (const float*)d_in[3];
    const float* W2 = (const float*)d_in[4];
    const float* b2 = (const float*)d_in[5];
    const float* W3 = (const float*)d_in[6];
    const float* b3 = (const float*)d_in[7];
    const float* W4 = (const float*)d_in[8];
    const float* b4 = (const float*)d_in[9];

    int N = in_sizes[0] / NODE_DIM;   // 100000
    int E = in_sizes[1] / 2;          // 1600000

    // ws: H [N*64] f32 | A [N*64] f32   (51.2 MB total)
    float* H = (float*)d_ws;
    float* A = H + (size_t)N * 64;

    int nb = (N + 63) / 64;
    int eb = (E + 255) / 256;

    float* out_type  = (float*)d_out;
    float* out_probs = (float*)d_out + E;

    hipLaunchKernelGGL(node_kernel, dim3(nb), dim3(256), 0, stream,
                       x, W1, b1, W2, b2, W3, H, A, N);
    hipLaunchKernelGGL(edge_kernel, dim3(eb), dim3(256), 0, stream,
                       ei, H, A, W3, b3, W4, b4, out_type, out_probs, E);
}